// Round 1
// baseline (1044.941 us; speedup 1.0000x reference)
//
#include <hip/hip_runtime.h>

// Sinkhorn attention, fp32 exp-domain implementation.
// Slabs: s = b*8 + h, 64 slabs of 1024x1024.
// E = exp(-S) lives in the attn region of d_out and is overwritten with
// attn = E*a_i*b_j*n by the final kernel.

#define MU (1.0f/1024.0f)   // mu == nu == 1/n
#define SCALE 0.125f        // 64^-0.5

// ---------------------------------------------------------------- K1: qkv = x @ Wqkv
// M=8192, K=512, N=1536. 128x128 tile, BK=16, 256 thr, 8x8 micro.
__global__ __launch_bounds__(256)
void k_gemm_qkv(const float* __restrict__ X, const float* __restrict__ W,
                float* __restrict__ Q) {
    __shared__ float aL[16][132];   // [k][m]
    __shared__ float bL[16][132];   // [k][n]
    const int n0 = blockIdx.x * 128;
    const int m0 = blockIdx.y * 128;
    const int t = threadIdx.x;
    const int tr = t >> 4, tc = t & 15;
    float acc[8][8] = {};
    for (int k0 = 0; k0 < 512; k0 += 16) {
#pragma unroll
        for (int q = 0; q < 2; ++q) {
            int p = t + 256 * q;               // 0..511
            int row = p >> 2, ks = (p & 3) * 4;
            float4 v = *reinterpret_cast<const float4*>(&X[(size_t)(m0 + row) * 512 + k0 + ks]);
            aL[ks + 0][row] = v.x; aL[ks + 1][row] = v.y;
            aL[ks + 2][row] = v.z; aL[ks + 3][row] = v.w;
        }
#pragma unroll
        for (int q = 0; q < 2; ++q) {
            int p = t + 256 * q;
            int kk = p >> 5, ns = (p & 31) * 4;
            *reinterpret_cast<float4*>(&bL[kk][ns]) =
                *reinterpret_cast<const float4*>(&W[(size_t)(k0 + kk) * 1536 + n0 + ns]);
        }
        __syncthreads();
#pragma unroll
        for (int kk = 0; kk < 16; ++kk) {
            float a8[8], b8[8];
#pragma unroll
            for (int r = 0; r < 8; ++r) a8[r] = aL[kk][tr * 8 + r];
#pragma unroll
            for (int c = 0; c < 8; ++c) b8[c] = bL[kk][tc * 8 + c];
#pragma unroll
            for (int r = 0; r < 8; ++r)
#pragma unroll
                for (int c = 0; c < 8; ++c)
                    acc[r][c] += a8[r] * b8[c];
        }
        __syncthreads();
    }
#pragma unroll
    for (int r = 0; r < 8; ++r)
#pragma unroll
        for (int c = 0; c < 8; c += 4) {
            float4 v = make_float4(acc[r][c], acc[r][c + 1], acc[r][c + 2], acc[r][c + 3]);
            *reinterpret_cast<float4*>(&Q[(size_t)(m0 + tr * 8 + r) * 1536 + n0 + tc * 8 + c]) = v;
        }
}

// ---------------------------------------------------------------- K2: E = exp(-QK^T*scale), r0 = rowsum(E)
// grid 4096: s = bi>>6, tile = bi&63 (8x8 tiles of 128x128). 256 thr, 8x8 micro, d in chunks of 16.
__global__ __launch_bounds__(256)
void k_qkT_exp(const float* __restrict__ QKV, float* __restrict__ E,
               float* __restrict__ r0) {
    __shared__ float qL[16][132];   // [d][i]
    __shared__ float kL[16][132];   // [d][j]
    __shared__ float rs[128];
    const int bi = blockIdx.x;
    const int s = bi >> 6, tile = bi & 63;
    const int i0 = (tile >> 3) * 128, j0 = (tile & 7) * 128;
    const int bb = s >> 3, h = s & 7;
    const int t = threadIdx.x, tr = t >> 4, tc = t & 15;
    const float* Qb = QKV + (size_t)bb * 1024 * 1536 + h * 64;
    const float* Kb = QKV + (size_t)bb * 1024 * 1536 + 512 + h * 64;
    float acc[8][8] = {};
    for (int d0 = 0; d0 < 64; d0 += 16) {
#pragma unroll
        for (int q = 0; q < 2; ++q) {
            int p = t + 256 * q;
            int row = p >> 2, ds = (p & 3) * 4;
            float4 v = *reinterpret_cast<const float4*>(&Qb[(size_t)(i0 + row) * 1536 + d0 + ds]);
            qL[ds + 0][row] = v.x; qL[ds + 1][row] = v.y;
            qL[ds + 2][row] = v.z; qL[ds + 3][row] = v.w;
            float4 w = *reinterpret_cast<const float4*>(&Kb[(size_t)(j0 + row) * 1536 + d0 + ds]);
            kL[ds + 0][row] = w.x; kL[ds + 1][row] = w.y;
            kL[ds + 2][row] = w.z; kL[ds + 3][row] = w.w;
        }
        __syncthreads();
#pragma unroll
        for (int d = 0; d < 16; ++d) {
            float a8[8], b8[8];
#pragma unroll
            for (int r = 0; r < 8; ++r) a8[r] = qL[d][tr * 8 + r];
#pragma unroll
            for (int c = 0; c < 8; ++c) b8[c] = kL[d][tc * 8 + c];
#pragma unroll
            for (int r = 0; r < 8; ++r)
#pragma unroll
                for (int c = 0; c < 8; ++c)
                    acc[r][c] += a8[r] * b8[c];
        }
        __syncthreads();
    }
    if (t < 128) rs[t] = 0.f;
    __syncthreads();
    float* Es = E + (size_t)s * 1024 * 1024;
#pragma unroll
    for (int r = 0; r < 8; ++r) {
        float e[8];
        float rsum = 0.f;
#pragma unroll
        for (int c = 0; c < 8; ++c) {
            e[c] = __expf(-acc[r][c] * SCALE);
            rsum += e[c];
        }
        size_t off = (size_t)(i0 + tr * 8 + r) * 1024 + j0 + tc * 8;
        *reinterpret_cast<float4*>(&Es[off])     = make_float4(e[0], e[1], e[2], e[3]);
        *reinterpret_cast<float4*>(&Es[off + 4]) = make_float4(e[4], e[5], e[6], e[7]);
        atomicAdd(&rs[tr * 8 + r], rsum);
    }
    __syncthreads();
    if (t < 128) atomicAdd(&r0[s * 1024 + i0 + t], rs[t]);
}

// ---------------------------------------------------------------- col pass: b_out = nu / (E^T a)
// grid 512: s = bi>>3, jc = (bi&7)*128. thread owns 1 col, 2 threads split rows.
__global__ __launch_bounds__(256)
void k_colpass(const float* __restrict__ E, const float* __restrict__ ain,
               float* __restrict__ bout, int raw) {
    __shared__ float aL[1024];
    __shared__ float part[256];
    const int bi = blockIdx.x;
    const int s = bi >> 3, jc = (bi & 7) * 128;
    const int t = threadIdx.x;
    const float* as = ain + s * 1024;
    for (int i = t; i < 1024; i += 256)
        aL[i] = raw ? (MU / as[i]) : as[i];
    __syncthreads();
    const int j = jc + (t & 127);
    const int half = t >> 7;
    const int ib = half * 512;
    const float* Ep = E + (size_t)s * 1024 * 1024 + (size_t)ib * 1024 + j;
    float c = 0.f;
#pragma unroll 8
    for (int i = 0; i < 512; ++i)
        c += Ep[(size_t)i * 1024] * aL[ib + i];
    part[t] = c;
    __syncthreads();
    if (t < 128)
        bout[s * 1024 + j] = MU / (part[t] + part[t + 128]);   // nu == MU
}

// ---------------------------------------------------------------- row pass: a_out = mu / (E b)
// grid 4096: s = bi>>6, i0 = (bi&63)*16. wave per row (4 rows each), float4 strided.
__global__ __launch_bounds__(256)
void k_rowpass(const float* __restrict__ E, const float* __restrict__ bin,
               float* __restrict__ aout) {
    __shared__ float bL[1024];
    const int bi = blockIdx.x;
    const int s = bi >> 6, i0 = (bi & 63) * 16;
    const int t = threadIdx.x;
    const float* bs = bin + s * 1024;
    for (int j = t; j < 1024; j += 256) bL[j] = bs[j];
    __syncthreads();
    const int w = t >> 6, l = t & 63;
#pragma unroll
    for (int rr = 0; rr < 4; ++rr) {
        const int i = i0 + w * 4 + rr;
        const float* Er = E + (size_t)s * 1024 * 1024 + (size_t)i * 1024;
        float sum = 0.f;
#pragma unroll
        for (int k = 0; k < 4; ++k) {
            int j4 = (l + k * 64) * 4;
            float4 e = *reinterpret_cast<const float4*>(&Er[j4]);
            sum += e.x * bL[j4] + e.y * bL[j4 + 1] + e.z * bL[j4 + 2] + e.w * bL[j4 + 3];
        }
#pragma unroll
        for (int off = 32; off; off >>= 1) sum += __shfl_xor(sum, off, 64);
        if (l == 0) aout[s * 1024 + i] = MU / sum;
    }
}

// ---------------------------------------------------------------- final: attn = E*a_i*b_j*n (in place), out_pre = attn @ V
// grid 512: s = bi>>3, i0 = (bi&7)*128. 256 thr; GEMM micro 8x4.
__global__ __launch_bounds__(256)
void k_finalize(float* __restrict__ E, const float* __restrict__ QKV,
                const float* __restrict__ a3, const float* __restrict__ b3,
                float* __restrict__ outp) {
    __shared__ float pT[64][132];   // attn tile transposed [j][i]
    __shared__ float vL[64][68];    // V chunk [j][d]
    __shared__ float aLs[128];
    __shared__ float bn[1024];
    const int bi = blockIdx.x;
    const int s = bi >> 3, i0 = (bi & 7) * 128;
    const int bb = s >> 3, h = s & 7;
    const int t = threadIdx.x;
    for (int j = t; j < 1024; j += 256) bn[j] = 1024.f * b3[s * 1024 + j];
    if (t < 128) aLs[t] = a3[s * 1024 + i0 + t];
    __syncthreads();
    const float* Vb = QKV + (size_t)bb * 1024 * 1536 + 1024 + h * 64;
    float* Es = E + (size_t)s * 1024 * 1024;
    const int tr = t >> 4, tc = t & 15;
    const int rowi = t >> 1;          // 0..127
    const int jh = (t & 1) * 32;
    float acc[8][4] = {};
    for (int jc = 0; jc < 1024; jc += 64) {
        // stage V chunk: 64x64
#pragma unroll
        for (int q = 0; q < 4; ++q) {
            int p = t + 256 * q;
            int vr = p >> 4, vd = (p & 15) * 4;
            *reinterpret_cast<float4*>(&vL[vr][vd]) =
                *reinterpret_cast<const float4*>(&Vb[(size_t)(jc + vr) * 1536 + vd]);
        }
        // attn tile: compute, write global in place, stash transposed in LDS
        float* Erow = &Es[(size_t)(i0 + rowi) * 1024 + jc + jh];
        const float ai = aLs[rowi];
#pragma unroll
        for (int q = 0; q < 8; ++q) {
            float4 e = *reinterpret_cast<float4*>(&Erow[q * 4]);
            int jj = jh + q * 4;
            float4 p4;
            p4.x = e.x * ai * bn[jc + jj];
            p4.y = e.y * ai * bn[jc + jj + 1];
            p4.z = e.z * ai * bn[jc + jj + 2];
            p4.w = e.w * ai * bn[jc + jj + 3];
            *reinterpret_cast<float4*>(&Erow[q * 4]) = p4;
            pT[jj][rowi] = p4.x; pT[jj + 1][rowi] = p4.y;
            pT[jj + 2][rowi] = p4.z; pT[jj + 3][rowi] = p4.w;
        }
        __syncthreads();
#pragma unroll
        for (int j = 0; j < 64; ++j) {
            float4 a0 = *reinterpret_cast<float4*>(&pT[j][tr * 8]);
            float4 a1 = *reinterpret_cast<float4*>(&pT[j][tr * 8 + 4]);
            float4 v4 = *reinterpret_cast<float4*>(&vL[j][tc * 4]);
            float a8[8] = {a0.x, a0.y, a0.z, a0.w, a1.x, a1.y, a1.z, a1.w};
#pragma unroll
            for (int r = 0; r < 8; ++r) {
                acc[r][0] += a8[r] * v4.x; acc[r][1] += a8[r] * v4.y;
                acc[r][2] += a8[r] * v4.z; acc[r][3] += a8[r] * v4.w;
            }
        }
        __syncthreads();
    }
#pragma unroll
    for (int r = 0; r < 8; ++r)
        *reinterpret_cast<float4*>(&outp[((size_t)s * 1024 + i0 + tr * 8 + r) * 64 + tc * 4]) =
            make_float4(acc[r][0], acc[r][1], acc[r][2], acc[r][3]);
}

// ---------------------------------------------------------------- out projection: Y = out_pre @ Wout + b
// M=8192, N=512, K=512. A gathered from [s][i][d] layout.
__global__ __launch_bounds__(256)
void k_outproj(const float* __restrict__ outp, const float* __restrict__ Wo,
               const float* __restrict__ bo, float* __restrict__ Y) {
    __shared__ float aL[16][132];
    __shared__ float bL[16][132];
    const int n0 = blockIdx.x * 128;
    const int m0 = blockIdx.y * 128;
    const int t = threadIdx.x;
    const int tr = t >> 4, tc = t & 15;
    float acc[8][8] = {};
    for (int k0 = 0; k0 < 512; k0 += 16) {
        const int h = k0 >> 6, db = k0 & 63;
#pragma unroll
        for (int q = 0; q < 2; ++q) {
            int p = t + 256 * q;
            int row = p >> 2, ks = (p & 3) * 4;
            int gm = m0 + row;
            int bb = gm >> 10, ii = gm & 1023;
            float4 v = *reinterpret_cast<const float4*>(
                &outp[((size_t)(bb * 8 + h) * 1024 + ii) * 64 + db + ks]);
            aL[ks + 0][row] = v.x; aL[ks + 1][row] = v.y;
            aL[ks + 2][row] = v.z; aL[ks + 3][row] = v.w;
        }
#pragma unroll
        for (int q = 0; q < 2; ++q) {
            int p = t + 256 * q;
            int kk = p >> 5, ns = (p & 31) * 4;
            *reinterpret_cast<float4*>(&bL[kk][ns]) =
                *reinterpret_cast<const float4*>(&Wo[(size_t)(k0 + kk) * 512 + n0 + ns]);
        }
        __syncthreads();
#pragma unroll
        for (int kk = 0; kk < 16; ++kk) {
            float a8[8], b8[8];
#pragma unroll
            for (int r = 0; r < 8; ++r) a8[r] = aL[kk][tr * 8 + r];
#pragma unroll
            for (int c = 0; c < 8; ++c) b8[c] = bL[kk][tc * 8 + c];
#pragma unroll
            for (int r = 0; r < 8; ++r)
#pragma unroll
                for (int c = 0; c < 8; ++c)
                    acc[r][c] += a8[r] * b8[c];
        }
        __syncthreads();
    }
#pragma unroll
    for (int r = 0; r < 8; ++r)
#pragma unroll
        for (int c = 0; c < 8; c += 4) {
            float4 v = make_float4(acc[r][c] + bo[n0 + tc * 8 + c],
                                   acc[r][c + 1] + bo[n0 + tc * 8 + c + 1],
                                   acc[r][c + 2] + bo[n0 + tc * 8 + c + 2],
                                   acc[r][c + 3] + bo[n0 + tc * 8 + c + 3]);
            *reinterpret_cast<float4*>(&Y[(size_t)(m0 + tr * 8 + r) * 512 + n0 + tc * 8 + c]) = v;
        }
}

extern "C" void kernel_launch(void* const* d_in, const int* in_sizes, int n_in,
                              void* d_out, int out_size, void* d_ws, size_t ws_size,
                              hipStream_t stream) {
    (void)in_sizes; (void)n_in; (void)out_size; (void)ws_size;
    const float* x    = (const float*)d_in[0];   // [8,1024,512]
    const float* Wqkv = (const float*)d_in[1];   // [512,1536]
    const float* Wout = (const float*)d_in[2];   // [512,512]
    const float* bout = (const float*)d_in[3];   // [512]
    float* out2 = (float*)d_out;                 // [8192,512]
    float* attn = out2 + (size_t)8192 * 512;     // [64][1024][1024], doubles as E

    float* ws   = (float*)d_ws;
    float* qkv  = ws;                            // 8192*1536
    float* outp = qkv + (size_t)8192 * 1536;     // 64*1024*64
    float* r0   = outp + (size_t)64 * 1024 * 64; // 64*1024
    float* abuf = r0 + 64 * 1024;                // 64*1024
    float* bbuf = abuf + 64 * 1024;              // 64*1024

    hipMemsetAsync(r0, 0, 64 * 1024 * sizeof(float), stream);
    k_gemm_qkv<<<dim3(12, 64), 256, 0, stream>>>(x, Wqkv, qkv);
    k_qkT_exp<<<4096, 256, 0, stream>>>(qkv, attn, r0);
    // iter1: u (from r0), v
    k_colpass<<<512, 256, 0, stream>>>(attn, r0, bbuf, 1);     // b1
    // iter2
    k_rowpass<<<4096, 256, 0, stream>>>(attn, bbuf, abuf);     // a2
    k_colpass<<<512, 256, 0, stream>>>(attn, abuf, bbuf, 0);   // b2
    // iter3
    k_rowpass<<<4096, 256, 0, stream>>>(attn, bbuf, abuf);     // a3
    k_colpass<<<512, 256, 0, stream>>>(attn, abuf, bbuf, 0);   // b3
    // finalize: attn in place + out_pre = attn @ V
    k_finalize<<<512, 256, 0, stream>>>(attn, qkv, abuf, bbuf, outp);
    k_outproj<<<dim3(4, 64), 256, 0, stream>>>(outp, Wout, bout, out2);
}

// Round 2
// 1029.889 us; speedup vs baseline: 1.0146x; 1.0146x over previous
//
#include <hip/hip_runtime.h>

// Sinkhorn attention, fp32 exp-domain implementation.
// Slabs: s = b*8 + h, 64 slabs of 1024x1024.
// E = exp(-S) lives in the attn region of d_out and is overwritten with
// attn = E*a_i*b_j*n by the final kernel.

#define MU (1.0f/1024.0f)   // mu == nu == 1/n
#define SCALE 0.125f        // 64^-0.5

typedef float f32x4 __attribute__((ext_vector_type(4)));

// ---------------------------------------------------------------- K1: qkv = x @ Wqkv
// M=8192, K=512, N=1536. 128x128 tile, BK=16, 256 thr, 8x8 micro.
__global__ __launch_bounds__(256)
void k_gemm_qkv(const float* __restrict__ X, const float* __restrict__ W,
                float* __restrict__ Q) {
    __shared__ float aL[16][132];   // [k][m]
    __shared__ float bL[16][132];   // [k][n]
    const int n0 = blockIdx.x * 128;
    const int m0 = blockIdx.y * 128;
    const int t = threadIdx.x;
    const int tr = t >> 4, tc = t & 15;
    float acc[8][8] = {};
    for (int k0 = 0; k0 < 512; k0 += 16) {
#pragma unroll
        for (int q = 0; q < 2; ++q) {
            int p = t + 256 * q;               // 0..511
            int row = p >> 2, ks = (p & 3) * 4;
            float4 v = *reinterpret_cast<const float4*>(&X[(size_t)(m0 + row) * 512 + k0 + ks]);
            aL[ks + 0][row] = v.x; aL[ks + 1][row] = v.y;
            aL[ks + 2][row] = v.z; aL[ks + 3][row] = v.w;
        }
#pragma unroll
        for (int q = 0; q < 2; ++q) {
            int p = t + 256 * q;
            int kk = p >> 5, ns = (p & 31) * 4;
            *reinterpret_cast<float4*>(&bL[kk][ns]) =
                *reinterpret_cast<const float4*>(&W[(size_t)(k0 + kk) * 1536 + n0 + ns]);
        }
        __syncthreads();
#pragma unroll
        for (int kk = 0; kk < 16; ++kk) {
            float a8[8], b8[8];
#pragma unroll
            for (int r = 0; r < 8; ++r) a8[r] = aL[kk][tr * 8 + r];
#pragma unroll
            for (int c = 0; c < 8; ++c) b8[c] = bL[kk][tc * 8 + c];
#pragma unroll
            for (int r = 0; r < 8; ++r)
#pragma unroll
                for (int c = 0; c < 8; ++c)
                    acc[r][c] += a8[r] * b8[c];
        }
        __syncthreads();
    }
#pragma unroll
    for (int r = 0; r < 8; ++r)
#pragma unroll
        for (int c = 0; c < 8; c += 4) {
            float4 v = make_float4(acc[r][c], acc[r][c + 1], acc[r][c + 2], acc[r][c + 3]);
            *reinterpret_cast<float4*>(&Q[(size_t)(m0 + tr * 8 + r) * 1536 + n0 + tc * 8 + c]) = v;
        }
}

// ---------------------------------------------------------------- K2: E = exp(-QK^T*scale), r0 = rowsum(E)
// grid 4096: s = bi>>6, tile = bi&63 (8x8 tiles of 128x128). 256 thr, 8x8 micro, d in chunks of 16.
__global__ __launch_bounds__(256)
void k_qkT_exp(const float* __restrict__ QKV, float* __restrict__ E,
               float* __restrict__ r0) {
    __shared__ float qL[16][132];   // [d][i]
    __shared__ float kL[16][132];   // [d][j]
    __shared__ float rs[128];
    const int bi = blockIdx.x;
    const int s = bi >> 6, tile = bi & 63;
    const int i0 = (tile >> 3) * 128, j0 = (tile & 7) * 128;
    const int bb = s >> 3, h = s & 7;
    const int t = threadIdx.x, tr = t >> 4, tc = t & 15;
    const float* Qb = QKV + (size_t)bb * 1024 * 1536 + h * 64;
    const float* Kb = QKV + (size_t)bb * 1024 * 1536 + 512 + h * 64;
    float acc[8][8] = {};
    for (int d0 = 0; d0 < 64; d0 += 16) {
#pragma unroll
        for (int q = 0; q < 2; ++q) {
            int p = t + 256 * q;
            int row = p >> 2, ds = (p & 3) * 4;
            float4 v = *reinterpret_cast<const float4*>(&Qb[(size_t)(i0 + row) * 1536 + d0 + ds]);
            qL[ds + 0][row] = v.x; qL[ds + 1][row] = v.y;
            qL[ds + 2][row] = v.z; qL[ds + 3][row] = v.w;
            float4 w = *reinterpret_cast<const float4*>(&Kb[(size_t)(j0 + row) * 1536 + d0 + ds]);
            kL[ds + 0][row] = w.x; kL[ds + 1][row] = w.y;
            kL[ds + 2][row] = w.z; kL[ds + 3][row] = w.w;
        }
        __syncthreads();
#pragma unroll
        for (int d = 0; d < 16; ++d) {
            float a8[8], b8[8];
#pragma unroll
            for (int r = 0; r < 8; ++r) a8[r] = qL[d][tr * 8 + r];
#pragma unroll
            for (int c = 0; c < 8; ++c) b8[c] = kL[d][tc * 8 + c];
#pragma unroll
            for (int r = 0; r < 8; ++r)
#pragma unroll
                for (int c = 0; c < 8; ++c)
                    acc[r][c] += a8[r] * b8[c];
        }
        __syncthreads();
    }
    if (t < 128) rs[t] = 0.f;
    __syncthreads();
    float* Es = E + (size_t)s * 1024 * 1024;
#pragma unroll
    for (int r = 0; r < 8; ++r) {
        float e[8];
        float rsum = 0.f;
#pragma unroll
        for (int c = 0; c < 8; ++c) {
            e[c] = __expf(-acc[r][c] * SCALE);
            rsum += e[c];
        }
        size_t off = (size_t)(i0 + tr * 8 + r) * 1024 + j0 + tc * 8;
        *reinterpret_cast<float4*>(&Es[off])     = make_float4(e[0], e[1], e[2], e[3]);
        *reinterpret_cast<float4*>(&Es[off + 4]) = make_float4(e[4], e[5], e[6], e[7]);
        atomicAdd(&rs[tr * 8 + r], rsum);
    }
    __syncthreads();
    if (t < 128) atomicAdd(&r0[s * 1024 + i0 + t], rs[t]);
}

// ---------------------------------------------------------------- col pass: cpart[p][s][j] = partial colsum of E*a
// grid 2048: s = bi>>5; rem=bi&31; jc=(rem>>2)*128; ic=(rem&3)*256.
// Inversion b = MU/c is done by the CONSUMER (rowpass / finalize preamble).
__global__ __launch_bounds__(256)
void k_colpass(const float* __restrict__ E, const float* __restrict__ ain,
               float* __restrict__ cpart, int raw) {
    __shared__ float aL[256];
    __shared__ float part[256];
    const int bi = blockIdx.x;
    const int s = bi >> 5;
    const int rem = bi & 31;
    const int jc = (rem >> 2) * 128;
    const int ic = (rem & 3) * 256;
    const int t = threadIdx.x;
    const float* as = ain + s * 1024 + ic;
    aL[t] = raw ? (MU / as[t]) : as[t];
    __syncthreads();
    const int j = jc + (t & 127);
    const int half = t >> 7;
    const int ib = ic + half * 128;
    const float* Ep = E + (size_t)s * 1024 * 1024 + (size_t)ib * 1024 + j;
    float c = 0.f;
#pragma unroll 8
    for (int i = 0; i < 128; ++i)
        c += Ep[(size_t)i * 1024] * aL[half * 128 + i];
    part[t] = c;
    __syncthreads();
    if (t < 128)
        cpart[(size_t)(rem & 3) * 65536 + s * 1024 + j] = part[t] + part[t + 128];
}

// ---------------------------------------------------------------- row pass: a_out = mu / (E b), b = MU / sum(cpart)
// grid 4096: s = bi>>6, i0 = (bi&63)*16. wave per row (4 rows each), float4 strided.
__global__ __launch_bounds__(256)
void k_rowpass(const float* __restrict__ E, const float* __restrict__ cpart,
               float* __restrict__ aout) {
    __shared__ float bL[1024];
    const int bi = blockIdx.x;
    const int s = bi >> 6, i0 = (bi & 63) * 16;
    const int t = threadIdx.x;
    for (int j = t; j < 1024; j += 256) {
        float c = cpart[s * 1024 + j] + cpart[65536 + s * 1024 + j]
                + cpart[131072 + s * 1024 + j] + cpart[196608 + s * 1024 + j];
        bL[j] = MU / c;
    }
    __syncthreads();
    const int w = t >> 6, l = t & 63;
#pragma unroll
    for (int rr = 0; rr < 4; ++rr) {
        const int i = i0 + w * 4 + rr;
        const float* Er = E + (size_t)s * 1024 * 1024 + (size_t)i * 1024;
        float sum = 0.f;
#pragma unroll
        for (int k = 0; k < 4; ++k) {
            int j4 = (l + k * 64) * 4;
            float4 e = *reinterpret_cast<const float4*>(&Er[j4]);
            sum += e.x * bL[j4] + e.y * bL[j4 + 1] + e.z * bL[j4 + 2] + e.w * bL[j4 + 3];
        }
#pragma unroll
        for (int off = 32; off; off >>= 1) sum += __shfl_xor(sum, off, 64);
        if (l == 0) aout[s * 1024 + i] = MU / sum;
    }
}

// ---------------------------------------------------------------- final: attn = E*a_i*b_j*n (in place), out_pre = attn @ V
// grid 1024: s = bi>>4, i0 = (bi&15)*64. 256 thr; j-chunks of 32; no partial buffers
// (each block owns complete rows). NT load/store on E/attn (last use, write-once).
__global__ __launch_bounds__(256)
void k_finalize(float* __restrict__ E, const float* __restrict__ QKV,
                const float* __restrict__ a3, const float* __restrict__ cpart,
                float* __restrict__ outp) {
    __shared__ float pT[32][68];    // attn chunk transposed [j][i]
    __shared__ float vL[32][68];    // V chunk [j][d]
    __shared__ float aLs[64];
    __shared__ float bn[1024];
    const int bi = blockIdx.x;
    const int s = bi >> 4, i0 = (bi & 15) * 64;
    const int bb = s >> 3, h = s & 7;
    const int t = threadIdx.x;
    for (int j = t; j < 1024; j += 256) {
        float c = cpart[s * 1024 + j] + cpart[65536 + s * 1024 + j]
                + cpart[131072 + s * 1024 + j] + cpart[196608 + s * 1024 + j];
        bn[j] = 1024.f * (MU / c);
    }
    if (t < 64) aLs[t] = a3[s * 1024 + i0 + t];
    __syncthreads();
    const float* Vb = QKV + (size_t)bb * 1024 * 1536 + 1024 + h * 64;
    float* Es = E + (size_t)s * 1024 * 1024;
    const int rowi = t >> 2;          // 0..63
    const int jh = (t & 3) * 8;       // 8 cols each
    const int tr = t >> 4, tc = t & 15;
    float acc[4][4] = {};
    for (int jc = 0; jc < 1024; jc += 32) {
        // stage V chunk 32x64
#pragma unroll
        for (int q = 0; q < 2; ++q) {
            int p = t + 256 * q;
            int vr = p >> 4, vd = (p & 15) * 4;
            *reinterpret_cast<float4*>(&vL[vr][vd]) =
                *reinterpret_cast<const float4*>(&Vb[(size_t)(jc + vr) * 1536 + vd]);
        }
        // attn: thread owns row i0+rowi, cols jh..jh+8 of this chunk
        f32x4* Erow = reinterpret_cast<f32x4*>(&Es[(size_t)(i0 + rowi) * 1024 + jc + jh]);
        const float ai = aLs[rowi];
#pragma unroll
        for (int q = 0; q < 2; ++q) {
            f32x4 e = __builtin_nontemporal_load(Erow + q);
            int jj = jh + q * 4;
            f32x4 p4;
            p4.x = e.x * ai * bn[jc + jj];
            p4.y = e.y * ai * bn[jc + jj + 1];
            p4.z = e.z * ai * bn[jc + jj + 2];
            p4.w = e.w * ai * bn[jc + jj + 3];
            __builtin_nontemporal_store(p4, Erow + q);
            pT[jj][rowi] = p4.x; pT[jj + 1][rowi] = p4.y;
            pT[jj + 2][rowi] = p4.z; pT[jj + 3][rowi] = p4.w;
        }
        __syncthreads();
#pragma unroll
        for (int j = 0; j < 32; ++j) {
            float4 a4 = *reinterpret_cast<float4*>(&pT[j][tr * 4]);
            float4 v4 = *reinterpret_cast<float4*>(&vL[j][tc * 4]);
            float a[4] = {a4.x, a4.y, a4.z, a4.w};
            float v[4] = {v4.x, v4.y, v4.z, v4.w};
#pragma unroll
            for (int r = 0; r < 4; ++r)
#pragma unroll
                for (int c = 0; c < 4; ++c)
                    acc[r][c] += a[r] * v[c];
        }
        __syncthreads();
    }
#pragma unroll
    for (int r = 0; r < 4; ++r)
        *reinterpret_cast<float4*>(&outp[((size_t)s * 1024 + i0 + tr * 4 + r) * 64 + tc * 4]) =
            make_float4(acc[r][0], acc[r][1], acc[r][2], acc[r][3]);
}

// ---------------------------------------------------------------- out projection: Y = out_pre @ Wout + b
// M=8192, N=512, K=512. A gathered from [s][i][d] layout.
__global__ __launch_bounds__(256)
void k_outproj(const float* __restrict__ outp, const float* __restrict__ Wo,
               const float* __restrict__ bo, float* __restrict__ Y) {
    __shared__ float aL[16][132];
    __shared__ float bL[16][132];
    const int n0 = blockIdx.x * 128;
    const int m0 = blockIdx.y * 128;
    const int t = threadIdx.x;
    const int tr = t >> 4, tc = t & 15;
    float acc[8][8] = {};
    for (int k0 = 0; k0 < 512; k0 += 16) {
        const int h = k0 >> 6, db = k0 & 63;
#pragma unroll
        for (int q = 0; q < 2; ++q) {
            int p = t + 256 * q;
            int row = p >> 2, ks = (p & 3) * 4;
            int gm = m0 + row;
            int bb = gm >> 10, ii = gm & 1023;
            float4 v = *reinterpret_cast<const float4*>(
                &outp[((size_t)(bb * 8 + h) * 1024 + ii) * 64 + db + ks]);
            aL[ks + 0][row] = v.x; aL[ks + 1][row] = v.y;
            aL[ks + 2][row] = v.z; aL[ks + 3][row] = v.w;
        }
#pragma unroll
        for (int q = 0; q < 2; ++q) {
            int p = t + 256 * q;
            int kk = p >> 5, ns = (p & 31) * 4;
            *reinterpret_cast<float4*>(&bL[kk][ns]) =
                *reinterpret_cast<const float4*>(&Wo[(size_t)(k0 + kk) * 512 + n0 + ns]);
        }
        __syncthreads();
#pragma unroll
        for (int kk = 0; kk < 16; ++kk) {
            float a8[8], b8[8];
#pragma unroll
            for (int r = 0; r < 8; ++r) a8[r] = aL[kk][tr * 8 + r];
#pragma unroll
            for (int c = 0; c < 8; ++c) b8[c] = bL[kk][tc * 8 + c];
#pragma unroll
            for (int r = 0; r < 8; ++r)
#pragma unroll
                for (int c = 0; c < 8; ++c)
                    acc[r][c] += a8[r] * b8[c];
        }
        __syncthreads();
    }
#pragma unroll
    for (int r = 0; r < 8; ++r)
#pragma unroll
        for (int c = 0; c < 8; c += 4) {
            float4 v = make_float4(acc[r][c] + bo[n0 + tc * 8 + c],
                                   acc[r][c + 1] + bo[n0 + tc * 8 + c + 1],
                                   acc[r][c + 2] + bo[n0 + tc * 8 + c + 2],
                                   acc[r][c + 3] + bo[n0 + tc * 8 + c + 3]);
            *reinterpret_cast<float4*>(&Y[(size_t)(m0 + tr * 8 + r) * 512 + n0 + tc * 8 + c]) = v;
        }
}

extern "C" void kernel_launch(void* const* d_in, const int* in_sizes, int n_in,
                              void* d_out, int out_size, void* d_ws, size_t ws_size,
                              hipStream_t stream) {
    (void)in_sizes; (void)n_in; (void)out_size; (void)ws_size;
    const float* x    = (const float*)d_in[0];   // [8,1024,512]
    const float* Wqkv = (const float*)d_in[1];   // [512,1536]
    const float* Wout = (const float*)d_in[2];   // [512,512]
    const float* bout = (const float*)d_in[3];   // [512]
    float* out2 = (float*)d_out;                 // [8192,512]
    float* attn = out2 + (size_t)8192 * 512;     // [64][1024][1024], doubles as E

    float* ws    = (float*)d_ws;
    float* qkv   = ws;                              // 8192*1536
    float* outp  = qkv + (size_t)8192 * 1536;       // 64*1024*64
    float* r0    = outp + (size_t)64 * 1024 * 64;   // 64*1024
    float* abuf  = r0 + 64 * 1024;                  // 64*1024
    float* cpart = abuf + 64 * 1024;                // 4 * 64*1024

    hipMemsetAsync(r0, 0, 64 * 1024 * sizeof(float), stream);
    k_gemm_qkv<<<dim3(12, 64), 256, 0, stream>>>(x, Wqkv, qkv);
    k_qkT_exp<<<4096, 256, 0, stream>>>(qkv, attn, r0);
    // iter1: u (from r0), v
    k_colpass<<<2048, 256, 0, stream>>>(attn, r0, cpart, 1);    // partial colsums for b1
    // iter2
    k_rowpass<<<4096, 256, 0, stream>>>(attn, cpart, abuf);     // a2
    k_colpass<<<2048, 256, 0, stream>>>(attn, abuf, cpart, 0);  // partial colsums for b2
    // iter3
    k_rowpass<<<4096, 256, 0, stream>>>(attn, cpart, abuf);     // a3
    k_colpass<<<2048, 256, 0, stream>>>(attn, abuf, cpart, 0);  // partial colsums for b3
    // finalize: attn in place + out_pre = attn @ V
    k_finalize<<<1024, 256, 0, stream>>>(attn, qkv, abuf, cpart, outp);
    k_outproj<<<dim3(4, 64), 256, 0, stream>>>(outp, Wout, bout, out2);
}